// Round 5
// baseline (68.197 us; speedup 1.0000x reference)
//
#include <hip/hip_runtime.h>
#include <hip/hip_bf16.h>
#include <math.h>

#define BB 8
#define SS 512
#define EE 128
#define HH 16
#define DKK 8

#define FMA4(ACC, S, W) do { (ACC).x += (S)*(W).x; (ACC).y += (S)*(W).y; \
                             (ACC).z += (S)*(W).z; (ACC).w += (S)*(W).w; } while(0)

// ---------------------------------------------------------------------------
// Kernel 1: QKV GEMM + bias + theta + quantum head. No LDS.
// grid (256, 3): blockIdx.x = 16-row tile of x, blockIdx.y = matrix (q/k/v).
// block 256 = 4 waves; per-lane tile 2 rows x 4 cols (cg = t&31, rg = t>>5).
// x rows read via global float4 (32 lanes share an address -> L1 broadcast);
// W columns perfectly coalesced global float4.
// Quantum head: 8-wire prefix cosine products; even/odd lane pair exchanges
// one 4-product via shfl_xor(1). Output layout (B, H, S, 8).
// ---------------------------------------------------------------------------
__global__ __launch_bounds__(256, 3) void k_qkvq(
    const float* __restrict__ x,
    const float* __restrict__ Wq, const float* __restrict__ bq,
    const float* __restrict__ Wk, const float* __restrict__ bk,
    const float* __restrict__ Wv, const float* __restrict__ bv,
    const float* __restrict__ theta,
    float* __restrict__ qh, float* __restrict__ kh, float* __restrict__ vh)
{
    const int t = threadIdx.x;
    const int m = blockIdx.y;
    const int row0 = blockIdx.x * 16;

    const int cg   = t & 31;
    const int col0 = cg * 4;
    const int rg   = t >> 5;          // 0..7
    const int r0   = rg * 2;

    const float* __restrict__ W  = (m == 0) ? Wq : (m == 1) ? Wk : Wv;
    const float* __restrict__ bb = (m == 0) ? bq : (m == 1) ? bk : bv;
    float* __restrict__ outp     = (m == 0) ? qh : (m == 1) ? kh : vh;

    // x rows r0, r0+1 of this tile (row stride = 32 float4)
    const float4* xr = (const float4*)(x + (size_t)(row0 + r0) * 128);

    float4 acc0 = *(const float4*)&bb[col0];
    float4 acc1 = acc0;

    #pragma unroll 4
    for (int k4 = 0; k4 < 32; ++k4) {
        const float4 xa = xr[k4];
        const float4 xb = xr[32 + k4];
        const float4 w0 = *(const float4*)&W[(k4 * 4 + 0) * 128 + col0];
        const float4 w1 = *(const float4*)&W[(k4 * 4 + 1) * 128 + col0];
        const float4 w2 = *(const float4*)&W[(k4 * 4 + 2) * 128 + col0];
        const float4 w3 = *(const float4*)&W[(k4 * 4 + 3) * 128 + col0];
        FMA4(acc0, xa.x, w0); FMA4(acc0, xa.y, w1);
        FMA4(acc0, xa.z, w2); FMA4(acc0, xa.w, w3);
        FMA4(acc1, xb.x, w0); FMA4(acc1, xb.y, w1);
        FMA4(acc1, xb.z, w2); FMA4(acc1, xb.w, w3);
    }

    const float4 th = *(const float4*)&theta[col0];
    const int h    = cg >> 1;
    const int half = cg & 1;          // 0: wires 0-3, 1: wires 4-7

    float4 accs[2] = {acc0, acc1};
    #pragma unroll
    for (int r = 0; r < 2; ++r) {
        float4 c;
        c.x = __cosf(accs[r].x + th.x);
        c.y = __cosf(accs[r].y + th.y);
        c.z = __cosf(accs[r].z + th.z);
        c.w = __cosf(accs[r].w + th.w);
        const float p0 = c.x;
        const float p1 = p0 * c.y;
        const float p2 = p1 * c.z;
        const float p3 = p2 * c.w;
        const float recv = __shfl_xor(p3, 1);
        float4 o;
        if (half == 0) {
            const float s123 = c.y * c.z * c.w;
            o.x = s123 * recv;   // wire 0: c1..c7
            o.y = p1;            // wire 1: c0 c1
            o.z = p2;            // wire 2
            o.w = p3;            // wire 3
        } else {
            o.x = recv * p0;     // wire 4: (c0..c3) c4
            o.y = recv * p1;
            o.z = recv * p2;
            o.w = recv * p3;
        }
        const int g  = row0 + r0 + r;
        const int b_ = g >> 9;
        const int s  = g & 511;
        *(float4*)&outp[(((size_t)b_ * HH + h) * SS + s) * DKK + half * 4] = o;
    }
}

// ---------------------------------------------------------------------------
// Kernel 2: attention partial pass.
// grid 512 = (bh 0..127) x (j-quarter 0..3); block 256 = 4 waves.
// Block stages its 128-row K/V j-quarter in LDS (8KB) -> 2 blocks/CU.
// Wave wv covers j sub-range [jq*128 + wv*32, +32) for ALL 512 q rows;
// lane owns R=8 q rows (L + 64r). Single-pass softmax partials
// (8 nums + den) written per (bh, jq, wv) straight to ws - no combine.
// ---------------------------------------------------------------------------
__global__ __launch_bounds__(256, 2) void k_attn(
    const float* __restrict__ qh, const float* __restrict__ kh,
    const float* __restrict__ vh, float* __restrict__ part)
{
    __shared__ float4 kk[256];    // 128 rows x 2 float4
    __shared__ float4 vv[256];

    const int t  = threadIdx.x;
    const int L  = t & 63;
    const int wv = __builtin_amdgcn_readfirstlane(t >> 6);
    const int bh = blockIdx.x >> 2;
    const int jq = blockIdx.x & 3;

    // stage this j-quarter of K/V (256 float4 each; 1 apiece per thread)
    {
        const float4* kg = (const float4*)kh + (size_t)bh * 1024 + jq * 256;
        const float4* vg = (const float4*)vh + (size_t)bh * 1024 + jq * 256;
        kk[t] = kg[t];
        vv[t] = vg[t];
    }

    // q rows L + 64r, r = 0..7
    float4 qa[8], qb[8];
    {
        const float4* qg = (const float4*)qh + (size_t)bh * 1024;
        #pragma unroll
        for (int r = 0; r < 8; ++r) {
            qa[r] = qg[(r * 64 + L) * 2];
            qb[r] = qg[(r * 64 + L) * 2 + 1];
        }
    }
    __syncthreads();

    float4 accA[8], accB[8];
    float  den[8];
    #pragma unroll
    for (int r = 0; r < 8; ++r) {
        accA[r] = make_float4(0.f, 0.f, 0.f, 0.f);
        accB[r] = make_float4(0.f, 0.f, 0.f, 0.f);
        den[r]  = 0.f;
    }
    const float scale = 0.35355339059327373f;   // 1/sqrt(8)
    const float4* kbase = kk + wv * 64;         // 32 rows x 2 float4
    const float4* vbase = vv + wv * 64;

    #pragma unroll 2
    for (int j = 0; j < 32; ++j) {
        const float4 k0 = kbase[2 * j];
        const float4 k1 = kbase[2 * j + 1];
        const float4 v0 = vbase[2 * j];
        const float4 v1 = vbase[2 * j + 1];
        #pragma unroll
        for (int r = 0; r < 8; ++r) {
            const float s = qa[r].x*k0.x + qa[r].y*k0.y + qa[r].z*k0.z + qa[r].w*k0.w
                          + qb[r].x*k1.x + qb[r].y*k1.y + qb[r].z*k1.z + qb[r].w*k1.w;
            const float e = __expf(s * scale);
            den[r] += e;
            FMA4(accA[r], e, v0);
            FMA4(accB[r], e, v1);
        }
    }

    // write partials: slot p = jq*4 + wv; row layout = 12 floats (3 float4)
    {
        float4* pf4 = (float4*)part;
        const size_t slotbase = ((size_t)bh * 16 + jq * 4 + wv) * 512;
        #pragma unroll
        for (int r = 0; r < 8; ++r) {
            const size_t o = (slotbase + r * 64 + L) * 3;
            pf4[o]     = accA[r];
            pf4[o + 1] = accB[r];
            pf4[o + 2] = make_float4(den[r], 0.f, 0.f, 0.f);
        }
    }
}

// ---------------------------------------------------------------------------
// Kernel 3: partial reduce + normalize + output projection.
// grid 256 x 256: block owns 16 output rows. Thread (rt = t>>4, h = t&15)
// sums the 16 partials for (row rt, head h), normalizes, writes the 16x128
// attnout tile to LDS. Then the 2x4-per-lane GEMM with Wo + bo.
// ---------------------------------------------------------------------------
__global__ __launch_bounds__(256) void k_out(
    const float* __restrict__ part, const float* __restrict__ Wo,
    const float* __restrict__ bo, float* __restrict__ out)
{
    __shared__ float hs[16][128];
    const int t = threadIdx.x;
    const int row0 = blockIdx.x * 16;

    // reduce partials
    {
        const int rt = t >> 4;
        const int h  = t & 15;
        const int g  = row0 + rt;
        const int b_ = g >> 9;
        const int s  = g & 511;
        const float4* pf4 = (const float4*)part;
        const size_t base = (((size_t)(b_ * 16 + h)) * 16) * 512 + s;
        float4 nA = make_float4(0.f, 0.f, 0.f, 0.f);
        float4 nB = make_float4(0.f, 0.f, 0.f, 0.f);
        float  dn = 0.f;
        #pragma unroll 4
        for (int p = 0; p < 16; ++p) {
            const size_t o = (base + (size_t)p * 512) * 3;
            const float4 a = pf4[o];
            const float4 b = pf4[o + 1];
            const float4 d = pf4[o + 2];
            nA.x += a.x; nA.y += a.y; nA.z += a.z; nA.w += a.w;
            nB.x += b.x; nB.y += b.y; nB.z += b.z; nB.w += b.w;
            dn   += d.x;
        }
        const float inv = 1.0f / dn;
        nA.x *= inv; nA.y *= inv; nA.z *= inv; nA.w *= inv;
        nB.x *= inv; nB.y *= inv; nB.z *= inv; nB.w *= inv;
        *(float4*)&hs[rt][h * 8]     = nA;
        *(float4*)&hs[rt][h * 8 + 4] = nB;
    }
    __syncthreads();

    // GEMM: 2 rows x 4 cols per lane
    const int cg   = t & 31;
    const int col0 = cg * 4;
    const int rg   = t >> 5;
    const int r0   = rg * 2;

    float4 acc0 = *(const float4*)&bo[col0];
    float4 acc1 = acc0;

    #pragma unroll 4
    for (int k4 = 0; k4 < 32; ++k4) {
        const float4 xa = ((const float4*)hs[r0 + 0])[k4];
        const float4 xb = ((const float4*)hs[r0 + 1])[k4];
        const float4 w0 = *(const float4*)&Wo[(k4 * 4 + 0) * 128 + col0];
        const float4 w1 = *(const float4*)&Wo[(k4 * 4 + 1) * 128 + col0];
        const float4 w2 = *(const float4*)&Wo[(k4 * 4 + 2) * 128 + col0];
        const float4 w3 = *(const float4*)&Wo[(k4 * 4 + 3) * 128 + col0];
        FMA4(acc0, xa.x, w0); FMA4(acc0, xa.y, w1);
        FMA4(acc0, xa.z, w2); FMA4(acc0, xa.w, w3);
        FMA4(acc1, xb.x, w0); FMA4(acc1, xb.y, w1);
        FMA4(acc1, xb.z, w2); FMA4(acc1, xb.w, w3);
    }

    *(float4*)&out[(size_t)(row0 + r0 + 0) * 128 + col0] = acc0;
    *(float4*)&out[(size_t)(row0 + r0 + 1) * 128 + col0] = acc1;
}

// ---------------------------------------------------------------------------
extern "C" void kernel_launch(void* const* d_in, const int* in_sizes, int n_in,
                              void* d_out, int out_size, void* d_ws, size_t ws_size,
                              hipStream_t stream)
{
    const float* x     = (const float*)d_in[0];
    const float* Wq    = (const float*)d_in[1];
    const float* bq    = (const float*)d_in[2];
    const float* Wk    = (const float*)d_in[3];
    const float* bk    = (const float*)d_in[4];
    const float* Wv    = (const float*)d_in[5];
    const float* bv    = (const float*)d_in[6];
    const float* Wo    = (const float*)d_in[7];
    const float* bo    = (const float*)d_in[8];
    const float* theta = (const float*)d_in[9];
    float* out = (float*)d_out;

    float* ws   = (float*)d_ws;
    float* qh   = ws;                  // B*H*S*8 = 524288 floats each
    float* kh   = ws + 524288;
    float* vh   = ws + 1048576;
    float* part = ws + 1572864;        // 128bh * 16slots * 512q * 12 floats

    k_qkvq<<<dim3(256, 3), 256, 0, stream>>>(x, Wq, bq, Wk, bk, Wv, bv,
                                             theta, qh, kh, vh);
    k_attn<<<512, 256, 0, stream>>>(qh, kh, vh, part);
    k_out <<<256, 256, 0, stream>>>(part, Wo, bo, out);
}